// Round 5
// baseline (251.794 us; speedup 1.0000x reference)
//
#include <hip/hip_runtime.h>
#include <math.h>
#include <stdint.h>

#define BATCH 64
#define N_OBJ 32
#define NP 8732
#define NC 81
#define THRESH 0.5f

// ---------------------------------------------------------------------------
// ws layout:
//   ovp    : float[BATCH*NP]   best IoU per (image, prior)
//   objp   : int  [BATCH*NP]   argmax object per (image, prior)
//   ce_neg : float[BATCH*NP]   CE of negatives (0 at positives)
//   pfo    : int  [BATCH*N_OBJ] argmax prior per (image, object)
//   n_pos  : int  [BATCH]
//   scal   : float[3]          {conf_pos, conf_hard_neg, loc_sum}
// ---------------------------------------------------------------------------

__device__ __forceinline__ float iou_box_prior(float x1, float y1, float x2, float y2,
                                               float areaA, float4 pr, float areaB) {
    float iw = fminf(x2, pr.z) - fmaxf(x1, pr.x); iw = fmaxf(iw, 0.f);
    float ih = fminf(y2, pr.w) - fmaxf(y1, pr.y); ih = fmaxf(ih, 0.f);
    float inter = iw * ih;
    return inter / (areaA + areaB - inter);
}

// per (image, prior): best object (first-occurrence argmax like jnp)
// also zeroes n_pos/scal (replaces k_zero; completes before k_ce runs)
__global__ void k_match_prior(const float* __restrict__ boxes,
                              const float* __restrict__ priors,
                              float* __restrict__ ovp, int* __restrict__ objp,
                              int* __restrict__ n_pos, float* __restrict__ scal) {
    int i = blockIdx.y;
    int t = threadIdx.x;
    if (blockIdx.x == 0 && i == 0) {
        if (t < BATCH) n_pos[t] = 0;
        if (t < 3) scal[t] = 0.f;
    }
    __shared__ float bx[N_OBJ * 4];
    if (t < N_OBJ * 4) bx[t] = boxes[i * N_OBJ * 4 + t];
    __syncthreads();
    int p = blockIdx.x * blockDim.x + t;
    if (p >= NP) return;
    float4 pr = ((const float4*)priors)[p];
    float areaB = (pr.z - pr.x) * (pr.w - pr.y);
    float best = -1.0f; int bestj = 0;
    #pragma unroll
    for (int j = 0; j < N_OBJ; ++j) {
        float x1 = bx[j * 4 + 0], y1 = bx[j * 4 + 1], x2 = bx[j * 4 + 2], y2 = bx[j * 4 + 3];
        float areaA = (x2 - x1) * (y2 - y1);
        float v = iou_box_prior(x1, y1, x2, y2, areaA, pr, areaB);
        if (v > best) { best = v; bestj = j; }   // strict > keeps FIRST max
    }
    ovp[i * NP + p] = best;
    objp[i * NP + p] = bestj;
}

// per (image, object): best prior (first-index tie-break)
__global__ void k_match_obj(const float* __restrict__ boxes,
                            const float* __restrict__ priors,
                            int* __restrict__ pfo) {
    int j = blockIdx.x, i = blockIdx.y;
    const float* bp = boxes + (i * N_OBJ + j) * 4;
    float x1 = bp[0], y1 = bp[1], x2 = bp[2], y2 = bp[3];
    float areaA = (x2 - x1) * (y2 - y1);
    float best = -1.f; int bestp = NP;
    for (int p = threadIdx.x; p < NP; p += blockDim.x) {
        float4 pr = ((const float4*)priors)[p];
        float areaB = (pr.z - pr.x) * (pr.w - pr.y);
        float v = iou_box_prior(x1, y1, x2, y2, areaA, pr, areaB);
        if (v > best) { best = v; bestp = p; }   // p ascending -> first max kept
    }
    __shared__ float sv[256];
    __shared__ int   si[256];
    int t = threadIdx.x;
    sv[t] = best; si[t] = bestp;
    __syncthreads();
    for (int s = 128; s > 0; s >>= 1) {
        if (t < s) {
            float v2 = sv[t + s]; int i2 = si[t + s];
            if (v2 > sv[t] || (v2 == sv[t] && i2 < si[t])) { sv[t] = v2; si[t] = i2; }
        }
        __syncthreads();
    }
    if (t == 0) pfo[i * N_OBJ + j] = si[0];
}

// sequential last-wins forced matches (matches .at[].set realization)
__global__ void k_force(const int* __restrict__ pfo,
                        float* __restrict__ ovp, int* __restrict__ objp) {
    int i = blockIdx.x * blockDim.x + threadIdx.x;
    if (i >= BATCH) return;
    for (int j = 0; j < N_OBJ; ++j) {
        int p = pfo[i * N_OBJ + j];
        objp[i * NP + p] = j;
        ovp[i * NP + p] = 1.0f;
    }
}

// barrier-free CE: 16 lanes per row, 4 rows per wave, all-static unroll,
// no LDS. shfl_xor(1,2,4,8) reduces within each 16-lane group.
__global__ void __launch_bounds__(256)
k_ce(const float* __restrict__ scores,
     const float* __restrict__ plocs,
     const float* __restrict__ boxes,
     const int*   __restrict__ labels,
     const float* __restrict__ priors,
     const float* __restrict__ ovp,
     const int*   __restrict__ objp,
     float* __restrict__ ce_neg,
     int* __restrict__ n_pos, float* __restrict__ scal) {
    int i    = blockIdx.y;
    int t    = threadIdx.x;
    int wid  = t >> 6;
    int lane = t & 63;
    int sub  = lane >> 4;          // row within wave quad
    int l    = lane & 15;          // lane within row group
    int p    = blockIdx.x * 16 + wid * 4 + sub;
    if (p >= NP) return;

    const float* row = scores + ((size_t)i * NP + p) * NC;
    float x0 = row[l];
    float x1 = row[l + 16];
    float x2 = row[l + 32];
    float x3 = row[l + 48];
    float x4 = row[l + 64];
    float x5 = (l == 0) ? row[80] : -INFINITY;

    float m = fmaxf(fmaxf(fmaxf(x0, x1), fmaxf(x2, x3)), fmaxf(x4, x5));
    m = fmaxf(m, __shfl_xor(m, 1));
    m = fmaxf(m, __shfl_xor(m, 2));
    m = fmaxf(m, __shfl_xor(m, 4));
    m = fmaxf(m, __shfl_xor(m, 8));

    float s = __expf(x0 - m) + __expf(x1 - m) + __expf(x2 - m)
            + __expf(x3 - m) + __expf(x4 - m) + __expf(x5 - m);
    s += __shfl_xor(s, 1);
    s += __shfl_xor(s, 2);
    s += __shfl_xor(s, 4);
    s += __shfl_xor(s, 8);

    if (l == 0) {
        float lse = m + __logf(s);
        int gi = i * NP + p;
        int   obj = objp[gi];
        float ov  = ovp[gi];
        int   lab = (ov < THRESH) ? 0 : labels[i * N_OBJ + obj];
        float ce = lse - row[lab];
        if (lab != 0) {
            atomicAdd(&n_pos[i], 1);
            atomicAdd(&scal[0], ce);
            const float* bp = boxes + (i * N_OBJ + obj) * 4;
            float bx1 = bp[0], by1 = bp[1], bx2 = bp[2], by2 = bp[3];
            float bcx = (bx1 + bx2) * 0.5f, bcy = (by1 + by2) * 0.5f;
            float bw = bx2 - bx1, bh = by2 - by1;
            float4 pr = ((const float4*)priors)[p];
            float g0 = (bcx - pr.x) / (pr.z / 10.0f);
            float g1 = (bcy - pr.y) / (pr.w / 10.0f);
            float g2 = logf(bw / pr.z) * 5.0f;
            float g3 = logf(bh / pr.w) * 5.0f;
            const float* pl = plocs + (size_t)gi * 4;
            float ll = fabsf(pl[0] - g0) + fabsf(pl[1] - g1)
                     + fabsf(pl[2] - g2) + fabsf(pl[3] - g3);
            atomicAdd(&scal[2], ll);
            ce_neg[gi] = 0.f;
        } else {
            ce_neg[gi] = ce;
        }
    }
}

// exact top-k sum per row; row held in registers (35/thread, static unroll),
// 31-pass binary search on the float bit pattern (all ce >= 0)
__global__ void __launch_bounds__(256)
k_topk(const float* __restrict__ ce_neg,
       const int* __restrict__ n_pos, float* __restrict__ scal) {
    int i = blockIdx.x;
    int t = threadIdx.x;
    float x[35];
    #pragma unroll
    for (int j = 0; j < 35; ++j) {
        int p = t + j * 256;
        x[j] = (p < NP) ? ce_neg[i * NP + p] : 0.f;
    }
    int k = 3 * n_pos[i];
    if (k > NP) k = NP;
    if (k <= 0) return;                     // uniform across block

    __shared__ int   cnt_s[4];
    __shared__ float sum_s[4];
    unsigned lo = 0u, hi = 0x7F800001u;     // cnt(lo)=all >= k ; cnt(hi)=0 < k
    while (hi - lo > 1u) {
        unsigned mid = lo + ((hi - lo) >> 1);
        int c = 0;
        #pragma unroll
        for (int j = 0; j < 35; ++j) c += (__float_as_uint(x[j]) >= mid) ? 1 : 0;
        #pragma unroll
        for (int off = 32; off; off >>= 1) c += __shfl_xor(c, off);
        if ((t & 63) == 0) cnt_s[t >> 6] = c;
        __syncthreads();
        int total = cnt_s[0] + cnt_s[1] + cnt_s[2] + cnt_s[3];
        __syncthreads();
        if (total >= k) lo = mid; else hi = mid;
    }
    float vk = __uint_as_float(lo);         // k-th largest (an actual element, or 0)

    float s = 0.f; int c = 0;
    #pragma unroll
    for (int j = 0; j < 35; ++j) {
        float v = x[j];
        if (v > vk) { s += v; c++; }
    }
    #pragma unroll
    for (int off = 32; off; off >>= 1) { s += __shfl_xor(s, off); c += __shfl_xor(c, off); }
    if ((t & 63) == 0) { sum_s[t >> 6] = s; cnt_s[t >> 6] = c; }
    __syncthreads();
    if (t == 0) {
        float st = sum_s[0] + sum_s[1] + sum_s[2] + sum_s[3];
        int   ct = cnt_s[0] + cnt_s[1] + cnt_s[2] + cnt_s[3];
        atomicAdd(&scal[1], st + (float)(k - ct) * vk);
    }
}

__global__ void k_final(const int* __restrict__ n_pos,
                        const float* __restrict__ scal, float* __restrict__ out) {
    int t = threadIdx.x;
    int v = (t < BATCH) ? n_pos[t] : 0;
    #pragma unroll
    for (int off = 32; off; off >>= 1) v += __shfl_xor(v, off);
    if (t == 0) {
        float nf = (float)v;
        out[0] = (scal[1] + scal[0]) / nf + scal[2] / (nf * 4.0f);
    }
}

extern "C" void kernel_launch(void* const* d_in, const int* in_sizes, int n_in,
                              void* d_out, int out_size, void* d_ws, size_t ws_size,
                              hipStream_t stream) {
    const float* plocs  = (const float*)d_in[0];
    const float* scores = (const float*)d_in[1];
    const float* boxes  = (const float*)d_in[2];
    const int*   labels = (const int*)d_in[3];
    const float* priors = (const float*)d_in[4];
    float* out = (float*)d_out;

    char* ws = (char*)d_ws;
    size_t bp = (size_t)BATCH * NP * 4;
    float* ovp    = (float*)(ws);
    int*   objp   = (int*)  (ws + bp);
    float* ce_neg = (float*)(ws + 2 * bp);
    int*   pfo    = (int*)  (ws + 3 * bp);
    int*   n_pos  = pfo + BATCH * N_OBJ;
    float* scal   = (float*)(n_pos + BATCH);

    hipLaunchKernelGGL(k_match_prior, dim3((NP + 255) / 256, BATCH), dim3(256), 0, stream,
                       boxes, priors, ovp, objp, n_pos, scal);
    hipLaunchKernelGGL(k_match_obj, dim3(N_OBJ, BATCH), dim3(256), 0, stream,
                       boxes, priors, pfo);
    hipLaunchKernelGGL(k_force, dim3(1), dim3(64), 0, stream, pfo, ovp, objp);
    hipLaunchKernelGGL(k_ce, dim3((NP + 15) / 16, BATCH), dim3(256), 0, stream,
                       scores, plocs, boxes, labels, priors, ovp, objp, ce_neg, n_pos, scal);
    hipLaunchKernelGGL(k_topk, dim3(BATCH), dim3(256), 0, stream, ce_neg, n_pos, scal);
    hipLaunchKernelGGL(k_final, dim3(1), dim3(64), 0, stream, n_pos, scal, out);
}

// Round 6
// 188.677 us; speedup vs baseline: 1.3345x; 1.3345x over previous
//
#include <hip/hip_runtime.h>
#include <math.h>
#include <stdint.h>

#define BATCH 64
#define N_OBJ 32
#define NP 8732
#define NC 81
#define THRESH 0.5f

// ---------------------------------------------------------------------------
// ws layout:
//   ovp    : float[BATCH*NP]   best IoU per (image, prior)
//   objp   : int  [BATCH*NP]   argmax object per (image, prior)
//   ce_neg : float[BATCH*NP]   CE of negatives (0 at positives)
//   pfo    : int  [BATCH*N_OBJ] argmax prior per (image, object)
//   n_pos  : int  [BATCH]
//   scal   : float[3]          {conf_pos, conf_hard_neg, loc_sum}
// ---------------------------------------------------------------------------

__device__ __forceinline__ float iou_box_prior(float x1, float y1, float x2, float y2,
                                               float areaA, float4 pr, float areaB) {
    float iw = fminf(x2, pr.z) - fmaxf(x1, pr.x); iw = fmaxf(iw, 0.f);
    float ih = fminf(y2, pr.w) - fmaxf(y1, pr.y); ih = fmaxf(ih, 0.f);
    float inter = iw * ih;
    return inter / (areaA + areaB - inter);
}

// per (image, prior): best object (first-occurrence argmax like jnp)
// also zeroes n_pos/scal (replaces k_zero; completes before k_ce runs)
__global__ void k_match_prior(const float* __restrict__ boxes,
                              const float* __restrict__ priors,
                              float* __restrict__ ovp, int* __restrict__ objp,
                              int* __restrict__ n_pos, float* __restrict__ scal) {
    int i = blockIdx.y;
    int t = threadIdx.x;
    if (blockIdx.x == 0 && i == 0) {
        if (t < BATCH) n_pos[t] = 0;
        if (t < 3) scal[t] = 0.f;
    }
    __shared__ float bx[N_OBJ * 4];
    if (t < N_OBJ * 4) bx[t] = boxes[i * N_OBJ * 4 + t];
    __syncthreads();
    int p = blockIdx.x * blockDim.x + t;
    if (p >= NP) return;
    float4 pr = ((const float4*)priors)[p];
    float areaB = (pr.z - pr.x) * (pr.w - pr.y);
    float best = -1.0f; int bestj = 0;
    #pragma unroll
    for (int j = 0; j < N_OBJ; ++j) {
        float x1 = bx[j * 4 + 0], y1 = bx[j * 4 + 1], x2 = bx[j * 4 + 2], y2 = bx[j * 4 + 3];
        float areaA = (x2 - x1) * (y2 - y1);
        float v = iou_box_prior(x1, y1, x2, y2, areaA, pr, areaB);
        if (v > best) { best = v; bestj = j; }   // strict > keeps FIRST max
    }
    ovp[i * NP + p] = best;
    objp[i * NP + p] = bestj;
}

// per (image, object): best prior (first-index tie-break)
__global__ void k_match_obj(const float* __restrict__ boxes,
                            const float* __restrict__ priors,
                            int* __restrict__ pfo) {
    int j = blockIdx.x, i = blockIdx.y;
    const float* bp = boxes + (i * N_OBJ + j) * 4;
    float x1 = bp[0], y1 = bp[1], x2 = bp[2], y2 = bp[3];
    float areaA = (x2 - x1) * (y2 - y1);
    float best = -1.f; int bestp = NP;
    for (int p = threadIdx.x; p < NP; p += blockDim.x) {
        float4 pr = ((const float4*)priors)[p];
        float areaB = (pr.z - pr.x) * (pr.w - pr.y);
        float v = iou_box_prior(x1, y1, x2, y2, areaA, pr, areaB);
        if (v > best) { best = v; bestp = p; }   // p ascending -> first max kept
    }
    __shared__ float sv[256];
    __shared__ int   si[256];
    int t = threadIdx.x;
    sv[t] = best; si[t] = bestp;
    __syncthreads();
    for (int s = 128; s > 0; s >>= 1) {
        if (t < s) {
            float v2 = sv[t + s]; int i2 = si[t + s];
            if (v2 > sv[t] || (v2 == sv[t] && i2 < si[t])) { sv[t] = v2; si[t] = i2; }
        }
        __syncthreads();
    }
    if (t == 0) pfo[i * N_OBJ + j] = si[0];
}

// sequential last-wins forced matches (matches .at[].set realization)
__global__ void k_force(const int* __restrict__ pfo,
                        float* __restrict__ ovp, int* __restrict__ objp) {
    int i = blockIdx.x * blockDim.x + threadIdx.x;
    if (i >= BATCH) return;
    for (int j = 0; j < N_OBJ; ++j) {
        int p = pfo[i * N_OBJ + j];
        objp[i * NP + p] = j;
        ovp[i * NP + p] = 1.0f;
    }
}

// one thread = one full row. 81 floats in registers (static unroll), no LDS,
// no shfl, no barriers. TLP hides load latency; exp throughput is trivial.
__global__ void __launch_bounds__(256)
k_ce(const float* __restrict__ scores,
     const float* __restrict__ plocs,
     const float* __restrict__ boxes,
     const int*   __restrict__ labels,
     const float* __restrict__ priors,
     const float* __restrict__ ovp,
     const int*   __restrict__ objp,
     float* __restrict__ ce_neg,
     int* __restrict__ n_pos, float* __restrict__ scal) {
    int i = blockIdx.y;
    int p = blockIdx.x * 256 + threadIdx.x;
    if (p >= NP) return;
    int gi = i * NP + p;

    int   obj = objp[gi];
    float ov  = ovp[gi];
    int   lab = (ov < THRESH) ? 0 : labels[i * N_OBJ + obj];

    const float* row = scores + (size_t)gi * NC;
    float slab = row[lab];          // issued early; L1-shared with row loads

    float x[NC];
    #pragma unroll
    for (int e = 0; e < NC; ++e) x[e] = row[e];

    float m0 = x[0], m1 = x[1], m2 = x[2], m3 = x[3];
    #pragma unroll
    for (int e = 4; e + 3 < NC; e += 4) {
        m0 = fmaxf(m0, x[e + 0]);
        m1 = fmaxf(m1, x[e + 1]);
        m2 = fmaxf(m2, x[e + 2]);
        m3 = fmaxf(m3, x[e + 3]);
    }
    m0 = fmaxf(m0, x[NC - 1]);
    float m = fmaxf(fmaxf(m0, m1), fmaxf(m2, m3));

    float s0 = 0.f, s1 = 0.f, s2 = 0.f, s3 = 0.f;
    #pragma unroll
    for (int e = 0; e + 3 < NC; e += 4) {
        s0 += __expf(x[e + 0] - m);
        s1 += __expf(x[e + 1] - m);
        s2 += __expf(x[e + 2] - m);
        s3 += __expf(x[e + 3] - m);
    }
    s0 += __expf(x[NC - 1] - m);
    float s = (s0 + s1) + (s2 + s3);

    float lse = m + __logf(s);
    float ce = lse - slab;

    if (lab != 0) {
        atomicAdd(&n_pos[i], 1);
        atomicAdd(&scal[0], ce);
        const float* bp = boxes + (i * N_OBJ + obj) * 4;
        float bx1 = bp[0], by1 = bp[1], bx2 = bp[2], by2 = bp[3];
        float bcx = (bx1 + bx2) * 0.5f, bcy = (by1 + by2) * 0.5f;
        float bw = bx2 - bx1, bh = by2 - by1;
        float4 pr = ((const float4*)priors)[p];
        float g0 = (bcx - pr.x) / (pr.z / 10.0f);
        float g1 = (bcy - pr.y) / (pr.w / 10.0f);
        float g2 = logf(bw / pr.z) * 5.0f;
        float g3 = logf(bh / pr.w) * 5.0f;
        const float* pl = plocs + (size_t)gi * 4;
        float ll = fabsf(pl[0] - g0) + fabsf(pl[1] - g1)
                 + fabsf(pl[2] - g2) + fabsf(pl[3] - g3);
        atomicAdd(&scal[2], ll);
        ce_neg[gi] = 0.f;
    } else {
        ce_neg[gi] = ce;
    }
}

// exact top-k sum per row; row held in registers (35/thread, static unroll),
// 31-pass binary search on the float bit pattern (all ce >= 0)
__global__ void __launch_bounds__(256)
k_topk(const float* __restrict__ ce_neg,
       const int* __restrict__ n_pos, float* __restrict__ scal) {
    int i = blockIdx.x;
    int t = threadIdx.x;
    float x[35];
    #pragma unroll
    for (int j = 0; j < 35; ++j) {
        int p = t + j * 256;
        x[j] = (p < NP) ? ce_neg[i * NP + p] : 0.f;
    }
    int k = 3 * n_pos[i];
    if (k > NP) k = NP;
    if (k <= 0) return;                     // uniform across block

    __shared__ int   cnt_s[4];
    __shared__ float sum_s[4];
    unsigned lo = 0u, hi = 0x7F800001u;     // cnt(lo)=all >= k ; cnt(hi)=0 < k
    while (hi - lo > 1u) {
        unsigned mid = lo + ((hi - lo) >> 1);
        int c = 0;
        #pragma unroll
        for (int j = 0; j < 35; ++j) c += (__float_as_uint(x[j]) >= mid) ? 1 : 0;
        #pragma unroll
        for (int off = 32; off; off >>= 1) c += __shfl_xor(c, off);
        if ((t & 63) == 0) cnt_s[t >> 6] = c;
        __syncthreads();
        int total = cnt_s[0] + cnt_s[1] + cnt_s[2] + cnt_s[3];
        __syncthreads();
        if (total >= k) lo = mid; else hi = mid;
    }
    float vk = __uint_as_float(lo);         // k-th largest (an actual element, or 0)

    float s = 0.f; int c = 0;
    #pragma unroll
    for (int j = 0; j < 35; ++j) {
        float v = x[j];
        if (v > vk) { s += v; c++; }
    }
    #pragma unroll
    for (int off = 32; off; off >>= 1) { s += __shfl_xor(s, off); c += __shfl_xor(c, off); }
    if ((t & 63) == 0) { sum_s[t >> 6] = s; cnt_s[t >> 6] = c; }
    __syncthreads();
    if (t == 0) {
        float st = sum_s[0] + sum_s[1] + sum_s[2] + sum_s[3];
        int   ct = cnt_s[0] + cnt_s[1] + cnt_s[2] + cnt_s[3];
        atomicAdd(&scal[1], st + (float)(k - ct) * vk);
    }
}

__global__ void k_final(const int* __restrict__ n_pos,
                        const float* __restrict__ scal, float* __restrict__ out) {
    int t = threadIdx.x;
    int v = (t < BATCH) ? n_pos[t] : 0;
    #pragma unroll
    for (int off = 32; off; off >>= 1) v += __shfl_xor(v, off);
    if (t == 0) {
        float nf = (float)v;
        out[0] = (scal[1] + scal[0]) / nf + scal[2] / (nf * 4.0f);
    }
}

extern "C" void kernel_launch(void* const* d_in, const int* in_sizes, int n_in,
                              void* d_out, int out_size, void* d_ws, size_t ws_size,
                              hipStream_t stream) {
    const float* plocs  = (const float*)d_in[0];
    const float* scores = (const float*)d_in[1];
    const float* boxes  = (const float*)d_in[2];
    const int*   labels = (const int*)d_in[3];
    const float* priors = (const float*)d_in[4];
    float* out = (float*)d_out;

    char* ws = (char*)d_ws;
    size_t bp = (size_t)BATCH * NP * 4;
    float* ovp    = (float*)(ws);
    int*   objp   = (int*)  (ws + bp);
    float* ce_neg = (float*)(ws + 2 * bp);
    int*   pfo    = (int*)  (ws + 3 * bp);
    int*   n_pos  = pfo + BATCH * N_OBJ;
    float* scal   = (float*)(n_pos + BATCH);

    hipLaunchKernelGGL(k_match_prior, dim3((NP + 255) / 256, BATCH), dim3(256), 0, stream,
                       boxes, priors, ovp, objp, n_pos, scal);
    hipLaunchKernelGGL(k_match_obj, dim3(N_OBJ, BATCH), dim3(256), 0, stream,
                       boxes, priors, pfo);
    hipLaunchKernelGGL(k_force, dim3(1), dim3(64), 0, stream, pfo, ovp, objp);
    hipLaunchKernelGGL(k_ce, dim3((NP + 255) / 256, BATCH), dim3(256), 0, stream,
                       scores, plocs, boxes, labels, priors, ovp, objp, ce_neg, n_pos, scal);
    hipLaunchKernelGGL(k_topk, dim3(BATCH), dim3(256), 0, stream, ce_neg, n_pos, scal);
    hipLaunchKernelGGL(k_final, dim3(1), dim3(64), 0, stream, n_pos, scal, out);
}